// Round 1
// 130.221 us; speedup vs baseline: 1.0116x; 1.0116x over previous
//
#include <hip/hip_runtime.h>

#define Bsz 128
#define Cd 81
#define Md 24
#define Nd 361
#define NAd 1805
#define RPW 16                    // na-rows per tile
#define NT 113                    // na tiles (112 full + 1 ragged, na0=1789)
#define GPB 4                     // b's (chunks) per group
#define NGRP 32                   // b-groups  (32 * 4 = 128 = Bsz)
#define NBLK_CLS (NT*NGRP)        // 3616 cls blocks: (tile t, b-group g of 4)
#define NOBJ (Bsz*Md)             // 3072
#define NBLK_ASSIGN (NOBJ/64)     // 48 assign blocks (placed FIRST in grid)
#define EPSF 1e-7f
#define IOU_THRF 0.6f

// ws float layout:
//   [0 .. 1805)        corr[NAd]      assign CE corrections (memset)
//   [1824 .. 3629)     gt[NAd]        (memset)
//   [3648 .. 3652)     acc: 0=noobj-cancel, 1=obj, 2=xy, 3=wh (memset)
//   [4096 .. 61856)    part[NAd][32]  CE partial per (na, b-group) - plain stores,
//                                     every slot written exactly once, no init
//   [61952 .. 65568)   noobj slot per cls block (written unconditionally)
#define OFF_CORR  0
#define OFF_GT    1824
#define OFF_ACC   3648
#define MEMSET_FLOATS 3652
#define OFF_PART  4096
#define OFF_NOOBJ 61952

#define EXP4(v) { v.x=__expf(v.x); v.y=__expf(v.y); v.z=__expf(v.z); v.w=__expf(v.w); }

// Single fused kernel:
//  - blocks [0,48): one object per thread, scattered gathers (latency-bound),
//    scheduled first so they overlap the BW-bound streaming blocks. Label is
//    computed inline from the one-hot row (dot with class index - exact).
//  - blocks [48, 48+3616): transposed CE sweep. Block (t,g) owns na-tile
//    [na0,na0+16) and b in [4g,4g+4). Each chunk (one b) = 1296 contiguous
//    floats through an aligned float4 window into LDS, exp in registers,
//    4-lane row reduce; 16 per-na CE values accumulate in REGISTERS across
//    the 4 b's, written with 16 plain stores. ZERO global atomics on the CE
//    path. 1-deep prefetch, single-wave blocks, no __syncthreads.
__global__ __launch_bounds__(64) void yolo_main(
        const float* __restrict__ conf,
        const float* __restrict__ pred_xy,
        const float* __restrict__ pred_wh,
        const float* __restrict__ cls_score,
        const float* __restrict__ true_label,
        const float* __restrict__ true_object,
        float* __restrict__ ws) {
    __shared__ float ex[1300];                  // 325 float4s: window + m slack
    const int lane = threadIdx.x;
    const int bid = blockIdx.x;

    if (bid >= NBLK_ASSIGN) {
        // ---------------- cls sweep branch ----------------
        const int cb = bid - NBLK_ASSIGN;
        const int t = cb >> 5, g = cb & 31;
        const int r = lane >> 2, h = lane & 3;
        float4* l4 = (float4*)ex;
        const int na0 = (t == NT - 1) ? (NAd - RPW) : t * RPW;   // ragged tail overlaps
        const int vmin = t * RPW;
        const bool validr = (na0 + r) >= vmin;               // row owned by this tile
        const bool validc = (lane < RPW) && ((na0 + lane) >= vmin);

        float accCE = 0.0f, nb = 0.0f;

        // prologue: b = 4g
        size_t s = ((size_t)(g * GPB) * NAd + na0) * Cd;
        size_t a0 = s & ~(size_t)3;
        int mcur = (int)(s & 3);
        const float4* gp = (const float4*)cls_score + (a0 >> 2);
        float4 u0 = gp[0 * 64 + lane];
        float4 u1 = gp[1 * 64 + lane];
        float4 u2 = gp[2 * 64 + lane];
        float4 u3 = gp[3 * 64 + lane];
        float4 u4 = gp[4 * 64 + lane];
        float4 u5 = gp[261 + lane];             // covers [261,325); <=16B overread, page-safe
        float cf = validc ? conf[(size_t)(g * GPB) * NAd + na0 + lane] : 0.5f;

        for (int it = 0; it < GPB; ++it) {
            EXP4(u0); EXP4(u1); EXP4(u2); EXP4(u3); EXP4(u4); EXP4(u5);
            l4[0 * 64 + lane] = u0;
            l4[1 * 64 + lane] = u1;
            l4[2 * 64 + lane] = u2;
            l4[3 * 64 + lane] = u3;
            l4[4 * 64 + lane] = u4;
            l4[261 + lane] = u5;                // dup region carries identical data
            __builtin_amdgcn_wave_barrier();

            // ---- prefetch next b (overlaps the reduce) ----
            float4 n0 = {}, n1 = {}, n2 = {}, n3 = {}, n4 = {}, n5 = {};
            float cfn = 0.0f; int mnext = 0;
            if (it < GPB - 1) {
                int b = g * GPB + it + 1;
                s = ((size_t)b * NAd + na0) * Cd;
                a0 = s & ~(size_t)3;
                mnext = (int)(s & 3);
                gp = (const float4*)cls_score + (a0 >> 2);
                n0 = gp[0 * 64 + lane];
                n1 = gp[1 * 64 + lane];
                n2 = gp[2 * 64 + lane];
                n3 = gp[3 * 64 + lane];
                n4 = gp[4 * 64 + lane];
                n5 = gp[261 + lane];
                cfn = validc ? conf[(size_t)b * NAd + na0 + lane] : 0.5f;
            }

            // ---- reduce current chunk: 4 lanes per row ----
            const float* p = ex + mcur + r * Cd;
            float sacc = 0.0f;
            #pragma unroll
            for (int j = 0; j < 21; j++) {
                int c0 = h * 21 + j;
                int cc = c0 < 81 ? c0 : 80;
                float w = (c0 < 81) ? 1.0f : 0.0f;
                sacc += p[cc] * w;
            }
            sacc += __shfl_xor(sacc, 1, 64);
            sacc += __shfl_xor(sacc, 2, 64);
            if (h == 0 && validr)
                accCE += __logf(sacc) - __logf(p[80]);      // lse - raw cs[80]
            if (validc) {
                float cp = fminf(fmaxf(cf, EPSF), 1.0f - EPSF);
                nb += -__logf(1.0f - cp);
            }

            u0 = n0; u1 = n1; u2 = n2; u3 = n3; u4 = n4; u5 = n5;
            cf = cfn; mcur = mnext;
        }

        if (h == 0 && validr)
            ws[OFF_PART + (size_t)(na0 + r) * NGRP + g] = accCE;  // unique slot, plain store

        #pragma unroll
        for (int off = 32; off > 0; off >>= 1) nb += __shfl_xor(nb, off, 64);
        if (lane == 0) ws[OFF_NOOBJ + cb] = nb;
    } else {
        // ---------------- assign branch: one object per thread ----------------
        const float AW[5] = {0.57273f, 1.87446f, 3.33843f, 7.88282f, 9.77052f};
        const float AH[5] = {0.677385f, 2.06253f, 5.47434f, 3.52778f, 9.16828f};
        const int idx = bid * 64 + lane;        // 0..3071 exact
        float* corr = ws + OFF_CORR;
        float* gt   = ws + OFF_GT;

        // label from one-hot row: dot with class index (exact: single 1.0 entry)
        const float* lrow = true_label + (size_t)idx * Cd;
        float labf = 0.0f;
        #pragma unroll
        for (int c = 1; c < Cd; c++) labf += lrow[c] * (float)c;
        int lab = (int)(labf + 0.5f);

        int b = idx / Md;
        const float4 to = ((const float4*)true_object)[idx];
        const float inv_ds = 1.0f / 32.0f;
        float gx = to.x * inv_ds, gy = to.y * inv_ds;
        float gw = to.z * inv_ds, gh = to.w * inv_ds;
        int ci = (int)gy, cj = (int)gx;                 // trunc == astype(int32)
        int cell = ci * 19 + cj;
        float garea = gw * gh;

        float best_iou = -1.0f; int best = 0; bool over[5];
        #pragma unroll
        for (int a = 0; a < 5; a++) {
            float inter = fminf(AW[a], gw) * fminf(AH[a], gh);
            float iou = inter / (AW[a] * AH[a] + garea - inter + EPSF);
            over[a] = iou > IOU_THRF;
            if (iou > best_iou) { best_iou = iou; best = a; }
        }

        int base_bn = (b * Nd + cell) * 5;
        float pwb = pred_wh[(size_t)(base_bn + best) * 2 + 0];
        float phb = pred_wh[(size_t)(base_bn + best) * 2 + 1];
        float inter = fminf(pwb, gw) * fminf(phb, gh);
        float iou_pg = inter / (pwb * phb + garea - inter + EPSF);
        float sw = 2.0f - (gw * (1.0f / 19.0f)) * (gh * (1.0f / 19.0f));

        float a0 = 0.f, a1 = 0.f, a2 = 0.f, a3 = 0.f;
        #pragma unroll
        for (int a = 0; a < 5; a++) {
            bool isb = (a == best);
            if (!(isb || over[a])) continue;            // om == 0 -> untouched
            int pos = base_bn + a;
            int na  = cell * 5 + a;
            float cp = fminf(fmaxf(conf[pos], EPSF), 1.0f - EPSF);
            a0 += __logf(1.0f - cp);                    // cancel base noobj term
            const float* cs = cls_score + (size_t)pos * Cd;
            atomicAdd(&corr[na], cs[Cd - 1] - cs[lab]);
            if (isb) {
                atomicAdd(&gt[na], 1.0f);
                a1 += -(iou_pg * __logf(cp) + (1.0f - iou_pg) * __logf(1.0f - cp));
                float px = pred_xy[(size_t)pos * 2 + 0], py = pred_xy[(size_t)pos * 2 + 1];
                a2 += sw * ((px - gx) * (px - gx) + (py - gy) * (py - gy));
                float pwa = pred_wh[(size_t)pos * 2 + 0], pha = pred_wh[(size_t)pos * 2 + 1];
                a3 += sw * ((pwa - gw) * (pwa - gw) + (pha - gh) * (pha - gh));
            }
        }

        #pragma unroll
        for (int off = 32; off > 0; off >>= 1) {
            a0 += __shfl_xor(a0, off, 64);
            a1 += __shfl_xor(a1, off, 64);
            a2 += __shfl_xor(a2, off, 64);
            a3 += __shfl_xor(a3, off, 64);
        }
        if (lane == 0) {
            atomicAdd(&ws[OFF_ACC + 0], a0);
            atomicAdd(&ws[OFF_ACC + 1], a1);
            atomicAdd(&ws[OFF_ACC + 2], a2);
            atomicAdd(&ws[OFF_ACC + 3], a3);
        }
    }
}

// Single block, coalesced L2-resident reductions only (~250 KB of reads).
__global__ __launch_bounds__(1024) void yolo_reduce(
        const float* __restrict__ ws, float* __restrict__ out) {
    __shared__ float red[2][16];
    const int tid = threadIdx.x;
    float nsum = 0.0f;
    for (int i = tid; i < NBLK_CLS; i += 1024) nsum += ws[OFF_NOOBJ + i];
    float ssum = 0.0f;
    const float4* part4 = (const float4*)(ws + OFF_PART);
    for (int na = tid; na < NAd; na += 1024) {
        const float4* p4 = part4 + (size_t)na * 8;
        float ce = 0.0f;
        #pragma unroll
        for (int k = 0; k < 8; k++) {
            float4 q = p4[k];
            ce += q.x + q.y + q.z + q.w;
        }
        ce += ws[OFF_CORR + na];
        ssum += ws[OFF_GT + na] * ce;
    }

    float v[2] = {nsum, ssum};
    #pragma unroll
    for (int k = 0; k < 2; k++) {
        float x = v[k];
        #pragma unroll
        for (int off = 32; off > 0; off >>= 1) x += __shfl_xor(x, off, 64);
        if ((tid & 63) == 0) red[k][tid >> 6] = x;
    }
    __syncthreads();
    if (tid == 0) {
        float t0 = 0.f, t1 = 0.f;
        #pragma unroll
        for (int w = 0; w < 16; w++) { t0 += red[0][w]; t1 += red[1][w]; }
        const float invB = 1.0f / (float)Bsz;
        float noobj = 1.0f * (t0 + ws[OFF_ACC + 0]) * invB;   // base + cancels
        float obj   = 5.0f * ws[OFF_ACC + 1] * invB;
        float xy    = 5.0f * ws[OFF_ACC + 2] * invB;
        float wh    = 5.0f * ws[OFF_ACC + 3] * invB;
        float score = 5.0f * t1 * invB;
        out[0] = noobj + obj + xy + wh + score;
        out[1] = noobj;
        out[2] = obj;
        out[3] = score;
        out[4] = xy;
        out[5] = wh;
    }
}

extern "C" void kernel_launch(void* const* d_in, const int* in_sizes, int n_in,
                              void* d_out, int out_size, void* d_ws, size_t ws_size,
                              hipStream_t stream) {
    // inputs: 0=epoch(unused), 1=conf, 2=pred_xy, 3=pred_wh, 4=cls_score,
    //         5=true_label, 6=true_object, 7=fm_cord(unused - cancels out)
    const float* conf    = (const float*)d_in[1];
    const float* pred_xy = (const float*)d_in[2];
    const float* pred_wh = (const float*)d_in[3];
    const float* cls     = (const float*)d_in[4];
    const float* tlabel  = (const float*)d_in[5];
    const float* tobject = (const float*)d_in[6];
    float* ws  = (float*)d_ws;
    float* out = (float*)d_out;

    hipMemsetAsync(ws, 0, MEMSET_FLOATS * sizeof(float), stream);

    yolo_main<<<NBLK_ASSIGN + NBLK_CLS, 64, 0, stream>>>(
        conf, pred_xy, pred_wh, cls, tlabel, tobject, ws);

    yolo_reduce<<<1, 1024, 0, stream>>>(ws, out);
}